// Round 3
// baseline (805.289 us; speedup 1.0000x reference)
//
#include <hip/hip_runtime.h>

#define BB 4
#define SS 2048
#define DD 2048
#define HH 16
#define HD 128
#define D3 6144
#define QKS 4096  // packed q|k row stride

typedef __attribute__((ext_vector_type(8))) short short8;
typedef __attribute__((ext_vector_type(4))) float float4v;

#define MFMA16(a, b, c) __builtin_amdgcn_mfma_f32_16x16x32_bf16(a, b, c, 0, 0, 0)

// async global->LDS, 16B per lane; LDS dest = wave-uniform base + lane*16
#define GLL16(g, l)                                                     \
    __builtin_amdgcn_global_load_lds(                                   \
        (__attribute__((address_space(1))) void*)(g),                   \
        (__attribute__((address_space(3))) void*)(l), 16, 0, 0)

__device__ __forceinline__ unsigned short f2b(float f) {
    union { float f; unsigned u; } v;
    v.f = f;
    unsigned r = v.u + 0x7FFFu + ((v.u >> 16) & 1u);  // RNE
    return (unsigned short)(r >> 16);
}

// ---------------- cast fp32 -> bf16 (4 elems/thread) ----------------
__global__ void cast_f32_bf16(const float* __restrict__ in,
                              unsigned short* __restrict__ out) {
    int i = (blockIdx.x * 256 + threadIdx.x) * 4;
    float4 v = *(const float4*)(in + i);
    ushort4 o;
    o.x = f2b(v.x); o.y = f2b(v.y); o.z = f2b(v.z); o.w = f2b(v.w);
    *(ushort4*)(out + i) = o;
}

// ------------- transpose + cast: in (R x C) fp32 -> out (C x R) bf16 -------------
__global__ void transpose_cast(const float* __restrict__ in,
                               unsigned short* __restrict__ out, int R, int C) {
    __shared__ float tile[32][33];
    int c0 = blockIdx.x * 32, r0 = blockIdx.y * 32;
    int tc = threadIdx.x & 31, tr = threadIdx.x >> 5;
#pragma unroll
    for (int i = 0; i < 4; ++i) {
        int r = tr + i * 8;
        tile[r][tc] = in[(size_t)(r0 + r) * C + c0 + tc];
    }
    __syncthreads();
#pragma unroll
    for (int i = 0; i < 4; ++i) {
        int wr = tr + i * 8;
        out[(size_t)(c0 + wr) * R + r0 + tc] = f2b(tile[tc][wr]);
    }
}

// ------------- bf16 GEMM (m97 structure), C = A (MxK) * Bt^T + bias -------------
// MODE 0: plain fp32 output (out-proj).
// MODE 1: QKV. n0<4096 -> rope applied, bf16 to qk[m][4096]. n0>=4096 -> V,
//         written transposed to vT[bh][d][s] via LDS chunk transpose.
template <int MODE>
__global__ __launch_bounds__(256) void gemm_bt(
    const unsigned short* __restrict__ A,   // M x K bf16
    const unsigned short* __restrict__ Bt,  // N x K bf16
    const float* __restrict__ bias,         // N fp32
    void* __restrict__ Cout,                // MODE0: fp32 MxN; MODE1: qk bf16 Mx4096
    unsigned short* __restrict__ vtout,     // MODE1: vT
    int M, int N, int K) {
    __shared__ unsigned short As[128 * 32];
    __shared__ unsigned short Bs[128 * 32];
    __shared__ unsigned short Et[MODE ? 32 * 136 : 8];  // V-transpose staging
    const int n0 = blockIdx.x * 128, m0 = blockIdx.y * 128;
    const int t = threadIdx.x, lane = t & 63, w = t >> 6;
    const int quad = lane >> 4, lr = lane & 15;
    const int wm = (w >> 1) * 64, wn = (w & 1) * 64;
    float4v acc[4][4] = {};
    const int srow = w * 32 + (lane >> 2);
    const int scol = (lane & 3) * 8;
    const unsigned short* Ag = A + (size_t)(m0 + srow) * K + scol;
    const unsigned short* Bg = Bt + (size_t)(n0 + srow) * K + scol;
    unsigned short* Asw = &As[(w * 32) * 32];
    unsigned short* Bsw = &Bs[(w * 32) * 32];
    for (int k0 = 0; k0 < K; k0 += 32) {
        __syncthreads();
        GLL16(Ag + k0, Asw);
        GLL16(Ag + k0 + (size_t)16 * K, Asw + 16 * 32);
        GLL16(Bg + k0, Bsw);
        GLL16(Bg + k0 + (size_t)16 * K, Bsw + 16 * 32);
        __syncthreads();
        short8 af[4], bf[4];
#pragma unroll
        for (int i = 0; i < 4; ++i)
            af[i] = *(const short8*)&As[(wm + i * 16 + lr) * 32 + quad * 8];
#pragma unroll
        for (int j = 0; j < 4; ++j)
            bf[j] = *(const short8*)&Bs[(wn + j * 16 + lr) * 32 + quad * 8];
#pragma unroll
        for (int i = 0; i < 4; ++i)
#pragma unroll
            for (int j = 0; j < 4; ++j)
                acc[i][j] = MFMA16(af[i], bf[j], acc[i][j]);
    }

    if (MODE == 0) {
#pragma unroll
        for (int j = 0; j < 4; ++j) {
            int n = n0 + wn + j * 16 + lr;
            float bv = bias[n];
#pragma unroll
            for (int i = 0; i < 4; ++i)
#pragma unroll
                for (int r = 0; r < 4; ++r) {
                    int m = m0 + wm + i * 16 + quad * 4 + r;
                    ((float*)Cout)[(size_t)m * N + n] = acc[i][j][r] + bv;
                }
        }
    } else if (n0 < 4096) {
        // ---- rope epilogue: rotate (2i,2i+1) pairs, write bf16 to qk ----
        unsigned short* qkp = (unsigned short*)Cout;
        const float L2IF = 0.2076205059304601f;    // log2(10000)/64
        const float R2PI = 0.15915494309189535f;   // 1/(2*pi)
        const int sbase = (m0 & 2047) + wm;
#pragma unroll
        for (int j = 0; j < 4; ++j) {
            int n = n0 + wn + j * 16 + lr;
            float bv = bias[n];
            int ip = (n & 127) >> 1;
            float invr = exp2f(-(float)ip * L2IF) * R2PI;
            float ssign = (n & 1) ? 1.0f : -1.0f;
#pragma unroll
            for (int i = 0; i < 4; ++i)
#pragma unroll
                for (int r = 0; r < 4; ++r) {
                    float v = acc[i][j][r] + bv;
                    float pv = __shfl_xor(v, 1);
                    float rev = (float)(sbase + i * 16 + quad * 4 + r) * invr;
                    float rr = rev - floorf(rev);
                    float sn = __builtin_amdgcn_sinf(rr);
                    float cs = __builtin_amdgcn_cosf(rr);
                    float outv = fmaf(v, cs, ssign * pv * sn);
                    int m = m0 + wm + i * 16 + quad * 4 + r;
                    qkp[(size_t)m * QKS + n] = f2b(outv);
                }
        }
    } else {
        // ---- V epilogue: write transposed to vT[bh][d][s], 4 chunks of 32 d ----
        int bh = ((m0 >> 11) << 4) + ((n0 - 4096) >> 7);
        unsigned short* vtp = vtout + (size_t)bh * HD * SS + (m0 & 2047);
#pragma unroll
        for (int c = 0; c < 4; ++c) {
            if (c) __syncthreads();
            if (wn == (c >> 1) * 64) {
#pragma unroll
                for (int jj = 0; jj < 2; ++jj) {
                    int j = (c & 1) * 2 + jj;
                    int n = n0 + wn + j * 16 + lr;
                    float bv = bias[n];
                    int dloc = jj * 16 + lr;
#pragma unroll
                    for (int i = 0; i < 4; ++i) {
                        uint2 pk;
                        pk.x = (unsigned)f2b(acc[i][j][0] + bv) |
                               ((unsigned)f2b(acc[i][j][1] + bv) << 16);
                        pk.y = (unsigned)f2b(acc[i][j][2] + bv) |
                               ((unsigned)f2b(acc[i][j][3] + bv) << 16);
                        *(uint2*)&Et[dloc * 136 + wm + i * 16 + quad * 4] = pk;
                    }
                }
            }
            __syncthreads();
            int dloc = t >> 3, sg = (t & 7) * 16;
#pragma unroll
            for (int u = 0; u < 2; ++u) {
                short8 vv = *(const short8*)&Et[dloc * 136 + sg + u * 8];
                *(short8*)(vtp + (size_t)(c * 32 + dloc) * SS + sg + u * 8) = vv;
            }
        }
    }
}

// ---------------- flash attention (causal), bf16 MFMA, fixed-max softmax -------
// grid: (S/128, B*H). 4 waves/block; wave w owns q rows [q0+32w, q0+32w+32).
__global__ __launch_bounds__(256) void attn_kernel(
    const unsigned short* __restrict__ qk,
    const unsigned short* __restrict__ vT,
    unsigned short* __restrict__ ctx) {
    __shared__ unsigned short Ks[64 * 128];    // [key][dim] swizzled chunks
    __shared__ unsigned short Vs[128 * 64];    // [dim][key] swizzled chunks
    __shared__ unsigned short Pw[4][32][72];   // per-wave P (row-major)
    const int bh = blockIdx.y, b = bh >> 4, h = bh & 15;
    const int q0 = (int)(gridDim.x - 1 - blockIdx.x) * 128;  // heavy blocks first
    const int t = threadIdx.x, w = t >> 6, lane = t & 63;
    const int quad = lane >> 4, lr = lane & 15;
    const int wq = q0 + w * 32;
    const unsigned short* qbase = qk + (size_t)b * SS * QKS + h * HD;
    const unsigned short* kbase = qbase + 2048;
    const unsigned short* vtb = vT + (size_t)bh * HD * SS;
    const float SCL2E = 0.12751741769976451f;   // (1/sqrt(128))*log2(e)
    const float NB16 = -23.083120654223414f;    // -16*log2(e)

    short8 qf[2][4];
#pragma unroll
    for (int m = 0; m < 2; ++m)
#pragma unroll
        for (int c = 0; c < 4; ++c)
            qf[m][c] = *(const short8*)(qbase + (size_t)(wq + m * 16 + lr) * QKS +
                                        c * 32 + quad * 8);

    float4v o[2][8] = {};
    float l_lane[2][4] = {};

    const int kr = lane >> 4, kg = lane & 15;  // Ks staging
    const int vr = lane >> 3, vg = lane & 7;   // Vs staging

    const int kend = q0 + 128;
    for (int k0 = 0; k0 < kend; k0 += 64) {
        __syncthreads();
#pragma unroll
        for (int u = 0; u < 4; ++u) {
            int row = w * 16 + u * 4 + kr;
            int g = kg ^ (row & 15);
            GLL16(kbase + (size_t)(k0 + row) * QKS + g * 8,
                  &Ks[(w * 16 + u * 4) * 128]);
        }
#pragma unroll
        for (int u = 0; u < 4; ++u) {
            int row = w * 32 + u * 8 + vr;
            int g = vg ^ (row & 7);
            GLL16(vtb + (size_t)row * SS + k0 + g * 8,
                  &Vs[(w * 32 + u * 8) * 64]);
        }
        __syncthreads();

        if (k0 > wq + 31) continue;  // tile fully masked for this wave

        // S = Q K^T : 2 m-subtiles x 4 k-subtiles
        float4v sc[2][4] = {};
#pragma unroll
        for (int c = 0; c < 4; ++c) {
            short8 kf[4];
#pragma unroll
            for (int ks = 0; ks < 4; ++ks)
                kf[ks] = *(const short8*)&Ks[(ks * 16 + lr) * 128 +
                                             (((c * 4 + quad) ^ lr) * 8)];
#pragma unroll
            for (int m = 0; m < 2; ++m)
#pragma unroll
                for (int ks = 0; ks < 4; ++ks)
                    sc[m][ks] = MFMA16(qf[m][c], kf[ks], sc[m][ks]);
        }

        // fixed-max softmax: p = exp2(s*scale*log2e - 16*log2e)
        const bool need_mask = (k0 + 63 > wq);
#pragma unroll
        for (int m = 0; m < 2; ++m)
#pragma unroll
            for (int ks = 0; ks < 4; ++ks) {
                int key = k0 + ks * 16 + lr;
#pragma unroll
                for (int r = 0; r < 4; ++r) {
                    float p = exp2f(fmaf(sc[m][ks][r], SCL2E, NB16));
                    if (need_mask) {
                        int qrow = wq + m * 16 + quad * 4 + r;
                        if (key > qrow) p = 0.0f;
                    }
                    l_lane[m][r] += p;
                    union { float f; unsigned u; } pu;
                    pu.f = p;
                    Pw[w][m * 16 + quad * 4 + r][ks * 16 + lr] =
                        (unsigned short)(pu.u >> 16);
                }
            }

        // O += P V
#pragma unroll
        for (int kc = 0; kc < 2; ++kc) {
            short8 pf0 = *(const short8*)&Pw[w][lr][kc * 32 + quad * 8];
            short8 pf1 = *(const short8*)&Pw[w][16 + lr][kc * 32 + quad * 8];
#pragma unroll
            for (int dc = 0; dc < 8; ++dc) {
                short8 vf = *(const short8*)&Vs[(dc * 16 + lr) * 64 +
                                                (((kc * 4 + quad) ^ (lr & 7)) * 8)];
                o[0][dc] = MFMA16(pf0, vf, o[0][dc]);
                o[1][dc] = MFMA16(pf1, vf, o[1][dc]);
            }
        }
    }

    float linv[2][4];
#pragma unroll
    for (int m = 0; m < 2; ++m)
#pragma unroll
        for (int r = 0; r < 4; ++r) {
            float l = l_lane[m][r];
            l += __shfl_xor(l, 1);
            l += __shfl_xor(l, 2);
            l += __shfl_xor(l, 4);
            l += __shfl_xor(l, 8);
            linv[m][r] = 1.0f / l;
        }
#pragma unroll
    for (int m = 0; m < 2; ++m)
#pragma unroll
        for (int dc = 0; dc < 8; ++dc)
#pragma unroll
            for (int r = 0; r < 4; ++r) {
                float val = o[m][dc][r] * linv[m][r];
                ctx[(size_t)(b * SS + wq + m * 16 + quad * 4 + r) * DD + h * HD +
                    dc * 16 + lr] = f2b(val);
            }
}

extern "C" void kernel_launch(void* const* d_in, const int* in_sizes, int n_in,
                              void* d_out, int out_size, void* d_ws, size_t ws_size,
                              hipStream_t stream) {
    const float* x = (const float*)d_in[0];
    const float* Wqkv_w = (const float*)d_in[2];
    const float* Wqkv_b = (const float*)d_in[3];
    const float* Wout_w = (const float*)d_in[4];
    const float* Wout_b = (const float*)d_in[5];
    float* out = (float*)d_out;

    unsigned short* x_bf = (unsigned short*)d_ws;   // 16,777,216 el
    unsigned short* wqkv_t = x_bf + 16777216;       // 12,582,912 el
    unsigned short* wout_t = wqkv_t + 12582912;     //  4,194,304 el
    unsigned short* qk = wout_t + 4194304;          // 33,554,432 el (8192 x 4096)
    unsigned short* vT = qk + 33554432;             // 16,777,216 el
    unsigned short* ctx = vT + 16777216;            // 16,777,216 el
    // total ws: 100,663,296 el * 2B = 192 MiB

    cast_f32_bf16<<<16384, 256, 0, stream>>>(x, x_bf);
    transpose_cast<<<dim3(192, 64), 256, 0, stream>>>(Wqkv_w, wqkv_t, 2048, 6144);
    transpose_cast<<<dim3(64, 64), 256, 0, stream>>>(Wout_w, wout_t, 2048, 2048);
    gemm_bt<1><<<dim3(48, 64), 256, 0, stream>>>(x_bf, wqkv_t, Wqkv_b, qk, vT,
                                                 8192, 6144, 2048);
    attn_kernel<<<dim3(16, 64), 256, 0, stream>>>(qk, vT, ctx);
    gemm_bt<0><<<dim3(16, 64), 256, 0, stream>>>(ctx, wout_t, Wout_b, out, nullptr,
                                                 8192, 2048, 2048);
}

// Round 4
// 750.617 us; speedup vs baseline: 1.0728x; 1.0728x over previous
//
#include <hip/hip_runtime.h>

#define BB 4
#define SS 2048
#define DD 2048
#define HH 16
#define HD 128
#define D3 6144

typedef __attribute__((ext_vector_type(8))) short short8;
typedef __attribute__((ext_vector_type(4))) float float4v;

#define MFMA16(a, b, c) __builtin_amdgcn_mfma_f32_16x16x32_bf16(a, b, c, 0, 0, 0)

// async global->LDS, 16B per lane; LDS dest = wave-uniform base + lane*16
#define GLL16(g, l)                                                     \
    __builtin_amdgcn_global_load_lds(                                   \
        (__attribute__((address_space(1))) void*)(g),                   \
        (__attribute__((address_space(3))) void*)(l), 16, 0, 0)

__device__ __forceinline__ unsigned short f2b(float f) {
    union { float f; unsigned u; } v;
    v.f = f;
    unsigned r = v.u + 0x7FFFu + ((v.u >> 16) & 1u);  // RNE
    return (unsigned short)(r >> 16);
}
__device__ __forceinline__ float b2f(unsigned short h) {
    union { unsigned u; float f; } v;
    v.u = ((unsigned)h) << 16;
    return v.f;
}

// ---------------- cast fp32 -> bf16 (4 elems/thread) ----------------
__global__ void cast_f32_bf16(const float* __restrict__ in,
                              unsigned short* __restrict__ out) {
    int i = (blockIdx.x * 256 + threadIdx.x) * 4;
    float4 v = *(const float4*)(in + i);
    ushort4 o;
    o.x = f2b(v.x); o.y = f2b(v.y); o.z = f2b(v.z); o.w = f2b(v.w);
    *(ushort4*)(out + i) = o;
}

// ------------- transpose + cast: in (R x C) fp32 -> out (C x R) bf16 -------------
__global__ void transpose_cast(const float* __restrict__ in,
                               unsigned short* __restrict__ out, int R, int C) {
    __shared__ float tile[32][33];
    int c0 = blockIdx.x * 32, r0 = blockIdx.y * 32;
    int tc = threadIdx.x & 31, tr = threadIdx.x >> 5;
#pragma unroll
    for (int i = 0; i < 4; ++i) {
        int r = tr + i * 8;
        tile[r][tc] = in[(size_t)(r0 + r) * C + c0 + tc];
    }
    __syncthreads();
#pragma unroll
    for (int i = 0; i < 4; ++i) {
        int wr = tr + i * 8;
        out[(size_t)(c0 + wr) * R + r0 + tc] = f2b(tile[tc][wr]);
    }
}

// ---------- transpose V within qkv -> vT[bh][d][s] (bf16) ----------
__global__ void vtrans(const unsigned short* __restrict__ qkv,
                       unsigned short* __restrict__ vT) {
    __shared__ unsigned short tile[32][33];
    int bh = blockIdx.z, b = bh >> 4, h = bh & 15;
    int s0 = blockIdx.x * 32, d0 = blockIdx.y * 32;
    int tc = threadIdx.x & 31, tr = threadIdx.x >> 5;
    const unsigned short* src = qkv + (size_t)b * SS * D3 + 4096 + h * HD;
#pragma unroll
    for (int i = 0; i < 4; ++i) {
        int sl = tr + i * 8;
        tile[sl][tc] = src[(size_t)(s0 + sl) * D3 + d0 + tc];
    }
    __syncthreads();
    unsigned short* dst = vT + (size_t)bh * HD * SS;
#pragma unroll
    for (int i = 0; i < 4; ++i) {
        int dl = tr + i * 8;
        dst[(size_t)(d0 + dl) * SS + s0 + tc] = tile[tc][dl];
    }
}

// ------------- bf16 GEMM (m97 structure), C = A (MxK) * Bt^T + bias -------------
// 128x128 tile, BK=32, global_load_lds width-16 staging, 4 waves, 64x64/wave.
template <int BF16OUT>
__global__ __launch_bounds__(256) void gemm_bt(
    const unsigned short* __restrict__ A,   // M x K bf16
    const unsigned short* __restrict__ Bt,  // N x K bf16
    const float* __restrict__ bias,         // N fp32
    void* __restrict__ Cout, int M, int N, int K) {
    __shared__ unsigned short As[128 * 32];
    __shared__ unsigned short Bs[128 * 32];
    const int n0 = blockIdx.x * 128, m0 = blockIdx.y * 128;
    const int t = threadIdx.x, lane = t & 63, w = t >> 6;
    const int quad = lane >> 4, lr = lane & 15;
    const int wm = (w >> 1) * 64, wn = (w & 1) * 64;
    float4v acc[4][4] = {};
    const int srow = w * 32 + (lane >> 2);
    const int scol = (lane & 3) * 8;
    const unsigned short* Ag = A + (size_t)(m0 + srow) * K + scol;
    const unsigned short* Bg = Bt + (size_t)(n0 + srow) * K + scol;
    unsigned short* Asw = &As[(w * 32) * 32];
    unsigned short* Bsw = &Bs[(w * 32) * 32];
    for (int k0 = 0; k0 < K; k0 += 32) {
        __syncthreads();
        GLL16(Ag + k0, Asw);
        GLL16(Ag + k0 + (size_t)16 * K, Asw + 16 * 32);
        GLL16(Bg + k0, Bsw);
        GLL16(Bg + k0 + (size_t)16 * K, Bsw + 16 * 32);
        __syncthreads();
        short8 af[4], bf[4];
#pragma unroll
        for (int i = 0; i < 4; ++i)
            af[i] = *(const short8*)&As[(wm + i * 16 + lr) * 32 + quad * 8];
#pragma unroll
        for (int j = 0; j < 4; ++j)
            bf[j] = *(const short8*)&Bs[(wn + j * 16 + lr) * 32 + quad * 8];
#pragma unroll
        for (int i = 0; i < 4; ++i)
#pragma unroll
            for (int j = 0; j < 4; ++j)
                acc[i][j] = MFMA16(af[i], bf[j], acc[i][j]);
    }
#pragma unroll
    for (int j = 0; j < 4; ++j) {
        int n = n0 + wn + j * 16 + lr;
        float bv = bias[n];
#pragma unroll
        for (int i = 0; i < 4; ++i)
#pragma unroll
            for (int r = 0; r < 4; ++r) {
                int m = m0 + wm + i * 16 + quad * 4 + r;
                float v = acc[i][j][r] + bv;
                if (BF16OUT)
                    ((unsigned short*)Cout)[(size_t)m * N + n] = f2b(v);
                else
                    ((float*)Cout)[(size_t)m * N + n] = v;
            }
    }
}

// ---------------- RoPE in-place on q,k of qkv (bf16), 4 pairs/thread -----------
__global__ void rope_kernel(unsigned short* __restrict__ qkv) {
    int tid = blockIdx.x * 256 + threadIdx.x;  // 2,097,152 threads
    int i4 = tid & 15;
    int h = (tid >> 4) & 15;
    int s = (tid >> 8) & 2047;
    int b = tid >> 19;
    size_t off = ((size_t)(b * SS + s)) * D3 + h * HD + i4 * 8;
    unsigned short* q = qkv + off;
    unsigned short* k = q + 2048;
    short8 qv = *(short8*)q, kv = *(short8*)k;
    const float L2IF = 0.2076205059304601f;    // log2(10000)/64
    const float R2PI = 0.15915494309189535f;   // 1/(2*pi)
    short8 qo, ko;
#pragma unroll
    for (int j = 0; j < 4; ++j) {
        int i = i4 * 4 + j;
        float invr = exp2f(-(float)i * L2IF) * R2PI;
        float rev = (float)s * invr;
        float rr = rev - floorf(rev);
        float sn = __builtin_amdgcn_sinf(rr);
        float cs = __builtin_amdgcn_cosf(rr);
        float a0 = b2f((unsigned short)qv[2 * j]);
        float a1 = b2f((unsigned short)qv[2 * j + 1]);
        qo[2 * j] = (short)f2b(a0 * cs - a1 * sn);
        qo[2 * j + 1] = (short)f2b(a1 * cs + a0 * sn);
        float c0 = b2f((unsigned short)kv[2 * j]);
        float c1 = b2f((unsigned short)kv[2 * j + 1]);
        ko[2 * j] = (short)f2b(c0 * cs - c1 * sn);
        ko[2 * j + 1] = (short)f2b(c1 * cs + c0 * sn);
    }
    *(short8*)q = qo;
    *(short8*)k = ko;
}

// ---------------- flash attention (causal), S^T form, 1-barrier pipeline -------
// grid (8, B*H): block handles q-block pair (x, 15-x) -> uniform 34 k-tiles.
// Ks/Vs double-buffered: prefetch tile i+1 while computing tile i.
__global__ __launch_bounds__(256) void attn_kernel(
    const unsigned short* __restrict__ qkv,
    const unsigned short* __restrict__ vT,
    unsigned short* __restrict__ ctx) {
    __shared__ unsigned short Ks[2][64 * 128];  // [key][dim] swizzled chunks
    __shared__ unsigned short Vs[2][128 * 64];  // [dim][key] swizzled chunks
    __shared__ unsigned short PT[4][32][40];    // per-wave P^T rows=q, 32-key chunk
    const int bh = blockIdx.y, b = bh >> 4, h = bh & 15;
    const int t = threadIdx.x, w = t >> 6, lane = t & 63;
    const int quad = lane >> 4, lr = lane & 15;
    const unsigned short* qbase = qkv + (size_t)b * SS * D3 + h * HD;
    const unsigned short* kbase = qbase + 2048;
    const unsigned short* vtb = vT + (size_t)bh * HD * SS;
    const float SCL2E = 0.12751741769976451f;   // (1/sqrt(128))*log2(e)
    const float NB16 = -23.083120654223414f;    // -16*log2(e)
    const int q0a = blockIdx.x * 128;
    const int q0b = (15 - (int)blockIdx.x) * 128;
    const int nta = (q0a >> 6) + 2, ntb = (q0b >> 6) + 2, ntot = nta + ntb;
    const int kr = lane >> 4, kg = lane & 15;
    const int vr = lane >> 3, vg = lane & 7;

    auto stage = [&](int k0, int bi) {
        unsigned short* KD = Ks[bi];
        unsigned short* VD = Vs[bi];
#pragma unroll
        for (int u = 0; u < 4; ++u) {
            int row = w * 16 + u * 4 + kr;
            int g = kg ^ (row & 15);
            GLL16(kbase + (size_t)(k0 + row) * D3 + g * 8,
                  &KD[(w * 16 + u * 4) * 128]);
        }
#pragma unroll
        for (int u = 0; u < 4; ++u) {
            int row = w * 32 + u * 8 + vr;
            int g = vg ^ (row & 7);
            GLL16(vtb + (size_t)row * SS + k0 + g * 8,
                  &VD[(w * 32 + u * 8) * 64]);
        }
    };

    int wq = q0a + w * 32;
    short8 qf[2][4];
#pragma unroll
    for (int m = 0; m < 2; ++m)
#pragma unroll
        for (int c = 0; c < 4; ++c)
            qf[m][c] = *(const short8*)(qbase + (size_t)(wq + m * 16 + lr) * D3 +
                                        c * 32 + quad * 8);

    float4v o[2][8] = {};
    float l_lane[2] = {0.f, 0.f};

    auto epilogue = [&]() {
#pragma unroll
        for (int m = 0; m < 2; ++m) {
            float l = l_lane[m];
            l += __shfl_xor(l, 16);
            l += __shfl_xor(l, 32);  // all lanes now hold l for q=lr
#pragma unroll
            for (int r = 0; r < 4; ++r) {
                float linv = 1.0f / __shfl(l, quad * 4 + r);
#pragma unroll
                for (int dc = 0; dc < 8; ++dc) {
                    float val = o[m][dc][r] * linv;
                    ctx[(size_t)(b * SS + wq + m * 16 + quad * 4 + r) * DD +
                        h * HD + dc * 16 + lr] = f2b(val);
                }
            }
        }
    };

    stage(0, 0);  // prologue prefetch

    for (int it = 0; it < ntot; ++it) {
        __syncthreads();  // drains stage(it) loads; fences buffer reuse
        int nit = it + 1;
        if (nit < ntot) stage((nit < nta ? nit : nit - nta) * 64, nit & 1);
        int k0 = (it < nta ? it : it - nta) * 64;
        const unsigned short* KB = Ks[it & 1];
        const unsigned short* VB = Vs[it & 1];

        if (k0 <= wq + 31) {
            // S^T = K Q^T : rows=key, cols=q. 4 key-subtiles x 2 q-subtiles.
            float4v sc[2][4] = {};
#pragma unroll
            for (int c = 0; c < 4; ++c) {
                short8 kf[4];
#pragma unroll
                for (int ks = 0; ks < 4; ++ks)
                    kf[ks] = *(const short8*)&KB[(ks * 16 + lr) * 128 +
                                                 (((c * 4 + quad) ^ lr) * 8)];
#pragma unroll
                for (int ks = 0; ks < 4; ++ks) {
                    sc[0][ks] = MFMA16(kf[ks], qf[0][c], sc[0][ks]);
                    sc[1][ks] = MFMA16(kf[ks], qf[1][c], sc[1][ks]);
                }
            }
            const bool nm = (k0 + 63 > wq);
#pragma unroll
            for (int kc = 0; kc < 2; ++kc) {
                // softmax on 32-key chunk; lane holds keys quad*4+r of q=lr
#pragma unroll
                for (int m = 0; m < 2; ++m)
#pragma unroll
                    for (int ks2 = 0; ks2 < 2; ++ks2) {
                        int ks = kc * 2 + ks2;
                        unsigned pk[2];
#pragma unroll
                        for (int rp = 0; rp < 2; ++rp) {
                            unsigned lo = 0, hi = 0;
#pragma unroll
                            for (int rr = 0; rr < 2; ++rr) {
                                int r = rp * 2 + rr;
                                float p = exp2f(fmaf(sc[m][ks][r], SCL2E, NB16));
                                if (nm) {
                                    int key = k0 + ks * 16 + quad * 4 + r;
                                    if (key > wq + m * 16 + lr) p = 0.0f;
                                }
                                l_lane[m] += p;
                                union { float f; unsigned u; } pu;
                                pu.f = p;
                                if (rr == 0) lo = pu.u >> 16;
                                else hi = pu.u >> 16;
                            }
                            pk[rp] = lo | (hi << 16);
                        }
                        uint2 pkk = {pk[0], pk[1]};
                        *(uint2*)&PT[w][m * 16 + lr][ks2 * 16 + quad * 4] = pkk;
                    }
                // O += P V for this 32-key chunk
                short8 pf0 = *(const short8*)&PT[w][lr][quad * 8];
                short8 pf1 = *(const short8*)&PT[w][16 + lr][quad * 8];
#pragma unroll
                for (int dc = 0; dc < 8; ++dc) {
                    short8 vf = *(const short8*)&VB[(dc * 16 + lr) * 64 +
                                                    (((kc * 4 + quad) ^ (lr & 7)) * 8)];
                    o[0][dc] = MFMA16(pf0, vf, o[0][dc]);
                    o[1][dc] = MFMA16(pf1, vf, o[1][dc]);
                }
            }
        }

        if (it == nta - 1) {
            // finish q-block a, switch to q-block b
            epilogue();
#pragma unroll
            for (int m = 0; m < 2; ++m) {
                l_lane[m] = 0.f;
#pragma unroll
                for (int dc = 0; dc < 8; ++dc) o[m][dc] = (float4v){0, 0, 0, 0};
            }
            wq = q0b + w * 32;
#pragma unroll
            for (int m = 0; m < 2; ++m)
#pragma unroll
                for (int c = 0; c < 4; ++c)
                    qf[m][c] = *(const short8*)(qbase +
                                                (size_t)(wq + m * 16 + lr) * D3 +
                                                c * 32 + quad * 8);
        }
    }
    epilogue();
}

extern "C" void kernel_launch(void* const* d_in, const int* in_sizes, int n_in,
                              void* d_out, int out_size, void* d_ws, size_t ws_size,
                              hipStream_t stream) {
    const float* x = (const float*)d_in[0];
    const float* Wqkv_w = (const float*)d_in[2];
    const float* Wqkv_b = (const float*)d_in[3];
    const float* Wout_w = (const float*)d_in[4];
    const float* Wout_b = (const float*)d_in[5];
    float* out = (float*)d_out;

    unsigned short* x_bf = (unsigned short*)d_ws;   // 16,777,216 el (reused as vT)
    unsigned short* wqkv_t = x_bf + 16777216;       // 12,582,912 el
    unsigned short* wout_t = wqkv_t + 12582912;     //  4,194,304 el
    unsigned short* qkv = wout_t + 4194304;         // 50,331,648 el
    unsigned short* ctx = qkv + 50331648;           // 16,777,216 el
    unsigned short* vT = x_bf;                      // alias: x_bf dead after QKV GEMM
    // total ws: 100,663,296 el * 2B = 192 MiB

    cast_f32_bf16<<<16384, 256, 0, stream>>>(x, x_bf);
    transpose_cast<<<dim3(192, 64), 256, 0, stream>>>(Wqkv_w, wqkv_t, 2048, 6144);
    transpose_cast<<<dim3(64, 64), 256, 0, stream>>>(Wout_w, wout_t, 2048, 2048);
    gemm_bt<1><<<dim3(48, 64), 256, 0, stream>>>(x_bf, wqkv_t, Wqkv_b, qkv,
                                                 8192, 6144, 2048);
    rope_kernel<<<8192, 256, 0, stream>>>(qkv);
    vtrans<<<dim3(64, 4, 64), 256, 0, stream>>>(qkv, vT);
    attn_kernel<<<dim3(8, 64), 256, 0, stream>>>(qkv, vT, ctx);
    gemm_bt<0><<<dim3(16, 64), 256, 0, stream>>>(ctx, wout_t, Wout_b, out,
                                                 8192, 2048, 2048);
}